// Round 6
// baseline (26.425 us; speedup 1.0000x reference)
//
#include <hip/hip_runtime.h>
#include <math.h>
#include <float.h>

// Problem constants (match reference setup_inputs)
#define BB 8
#define NN 2048
#define BN (BB * NN)
#define BLK 256
#define QSPLIT 8                // query slices per (task,b): 8 * 256 = 2048
#define QSLICE 256              // queries per block (1 per thread, pre-compaction)
#define CSPLIT 16               // candidate splits per (task,batch)
#define CCHUNK 128              // candidates staged per block (pre-compaction)

// Workspace layout (minpart slots for VALID queries written every call; invalid
// slots are never read without a mask-select; no init kernel needed):
//   float minpart[CSPLIT][2*BN]   @ 0          (2 MB)
//   float champart[128]           @ 2 MB
//   float l1part[64]              @ +512
//   float cntpart[64]             @ +768
//   uint  counter                 @ +1024      (zeroed by k_main block 0)
#define MINPART_FLOATS (CSPLIT * 2 * BN)

__global__ __launch_bounds__(BLK) void k_main(const float* __restrict__ pred,
                                              const float* __restrict__ target,
                                              const float* __restrict__ points,
                                              const int* __restrict__ mask,
                                              float* __restrict__ minpart,
                                              float* __restrict__ l1part,
                                              float* __restrict__ cntpart,
                                              unsigned int* __restrict__ counter) {
    // bid bits: cs(4) | qs(3) | b(3) | task(1)  -> 2048 blocks
    int bid = blockIdx.x;
    int cs = bid & (CSPLIT - 1);
    int qs = (bid >> 4) & (QSPLIT - 1);
    int b = (bid >> 7) & 7;
    int task = bid >> 10;  // 0: query=clean(points+target), cand=predp(points+pred)
                           // 1: query=predp,               cand=clean
    int t = threadIdx.x;
    int lane = t & 63, w = t >> 6;

    if (bid == 0 && t == 0) *counter = 0u;  // ticket reset for k_redfin (stream-ordered)

    const float* dq = task ? pred : target;   // query delta
    const float* dc = task ? target : pred;   // candidate delta

    __shared__ float4 cand[CCHUNK + 8];       // +8: padding slots to multiple of 8
    __shared__ float qlx[BLK], qly[BLK], qlz[BLK];
    __shared__ unsigned char qidx[BLK];
    __shared__ int cnts[8];   // [0..3] per-wave valid-query counts, [4..5] cand counts

    // ---- query load (original index) ----
    int gq = b * NN + qs * QSLICE + t;
    size_t gq3 = (size_t)gq * 3;
    int qm = mask[gq];
    float qx = points[gq3 + 0] + dq[gq3 + 0];
    float qy = points[gq3 + 1] + dq[gq3 + 1];
    float qz = points[gq3 + 2] + dq[gq3 + 2];

    // ---- fused masked-L1 + valid-count: 64 blocks (task0, cs0), 1 pt/thread ----
    if (task == 0 && cs == 0) {
        float m = (float)qm;
        float s = (fabsf(pred[gq3 + 0] - target[gq3 + 0]) +
                   fabsf(pred[gq3 + 1] - target[gq3 + 1]) +
                   fabsf(pred[gq3 + 2] - target[gq3 + 2])) * (1.0f / 3.0f) * m;
        float c = m;
        for (int off = 32; off; off >>= 1) {
            s += __shfl_down(s, off, 64);
            c += __shfl_down(c, off, 64);
        }
        __shared__ float ls[4], lc[4];
        if (lane == 0) { ls[w] = s; lc[w] = c; }
        __syncthreads();   // block-uniform branch (task, cs are block constants)
        if (t == 0) {
            l1part[b * QSPLIT + qs]  = ls[0] + ls[1] + ls[2] + ls[3];
            cntpart[b * QSPLIT + qs] = lc[0] + lc[1] + lc[2] + lc[3];
        }
    }

    // ---- query compaction ballot ----
    unsigned long long balq = __ballot(qm != 0);
    int myq = __popcll(balq & ((1ull << lane) - 1));
    if (lane == 0) cnts[w] = __popcll(balq);

    // ---- candidate load + compaction ballot (threads 0..127 = waves 0,1) ----
    int cm = 0;
    float cx = 0.f, cy = 0.f, cz = 0.f;
    if (t < CCHUNK) {
        int g = b * NN + cs * CCHUNK + t;
        size_t g3 = (size_t)g * 3;
        cm = mask[g];
        if (cm) {
            cx = points[g3 + 0] + dc[g3 + 0];
            cy = points[g3 + 1] + dc[g3 + 1];
            cz = points[g3 + 2] + dc[g3 + 2];
        }
    }
    unsigned long long balc = __ballot(cm != 0);
    int myc = __popcll(balc & ((1ull << lane) - 1));
    if (t < CCHUNK && lane == 0) cnts[4 + w] = __popcll(balc);
    __syncthreads();

    int nQ = cnts[0] + cnts[1] + cnts[2] + cnts[3];
    int nC = cnts[4] + cnts[5];
    int qbase = 0;
    for (int i = 0; i < w; ++i) qbase += cnts[i];
    if (qm) {
        int s = qbase + myq;
        qlx[s] = qx; qly[s] = qy; qlz[s] = qz;
        qidx[s] = (unsigned char)t;
    }
    if (t < CCHUNK && cm) {
        int s = (w ? cnts[4] : 0) + myc;
        cand[s] = make_float4(cx, cy, cz, 0.f);
    }
    int nCp = (nC + 7) & ~7;             // pad to multiple of 8 with losing dummies
    if (t < nCp - nC) cand[nC + t] = make_float4(1e30f, 1e30f, 1e30f, 0.f);
    __syncthreads();

    // ---- main loop over valid pairs only (~4x fewer than unmasked) ----
    if (t < nQ) {
        float ax = qlx[t], ay = qly[t], az = qlz[t];
        float mn = FLT_MAX;
        #pragma unroll 4
        for (int j = 0; j < nCp; j += 2) {
            float4 c0 = cand[j];       // broadcast ds_read_b128, conflict-free
            float4 c1 = cand[j + 1];
            float d0 = fabsf(ax - c0.x) + fabsf(ay - c0.y) + fabsf(az - c0.z);
            float d1 = fabsf(ax - c1.x) + fabsf(ay - c1.y) + fabsf(az - c1.z);
            mn = fminf(fminf(d0, d1), mn);   // v_min3_f32; min is order-exact
        }
        // distinct slot per (cs, task, b, original query)
        minpart[(size_t)cs * (2 * BN) + (size_t)task * BN + b * NN
                + qs * QSLICE + qidx[t]] = mn;
    }
}

__global__ __launch_bounds__(BLK) void k_redfin(const float* __restrict__ minpart,
                                                const int* __restrict__ mask,
                                                const float* __restrict__ l1part,
                                                const float* __restrict__ cntpart,
                                                float* __restrict__ champart,
                                                unsigned int* __restrict__ counter,
                                                float* __restrict__ out) {
    // 128 blocks: task(1) | b(3) | s(3); each covers 256 queries, 1 per thread
    int tb = blockIdx.x;
    int s8 = tb & 7;
    int b = (tb >> 3) & 7;
    int task = tb >> 6;
    int t = threadIdx.x;

    int qi = s8 * BLK + t;
    size_t idx = (size_t)task * BN + b * NN + qi;
    float mn = minpart[idx];
    #pragma unroll
    for (int cs = 1; cs < CSPLIT; ++cs)
        mn = fminf(mn, minpart[(size_t)cs * (2 * BN) + idx]);
    // select, not multiply: invalid-query slots are never written (garbage/NaN-safe)
    float v = (mask[b * NN + qi] != 0) ? mn : 0.f;

    for (int off = 32; off; off >>= 1) v += __shfl_down(v, off, 64);

    __shared__ float ls[4];
    __shared__ int isLast;
    __shared__ float ch[128];
    if ((t & 63) == 0) ls[t >> 6] = v;
    __syncthreads();
    if (t == 0) {
        float bs = ls[0] + ls[1] + ls[2] + ls[3];
        __hip_atomic_store(&champart[tb], bs, __ATOMIC_RELEASE, __HIP_MEMORY_SCOPE_AGENT);
        int ticket = __hip_atomic_fetch_add(counter, 1u, __ATOMIC_ACQ_REL, __HIP_MEMORY_SCOPE_AGENT);
        isLast = (ticket == 127);
    }
    __syncthreads();
    if (!isLast) return;

    // last block finalizes
    if (t < 128) ch[t] = __hip_atomic_load(&champart[t], __ATOMIC_ACQUIRE, __HIP_MEMORY_SCOPE_AGENT);
    __syncthreads();
    if (t == 0) {
        double cnt[BB], msum = 0.0, l1num = 0.0;
        for (int b2 = 0; b2 < BB; ++b2) {
            double cb = 0.0;
            for (int k = 0; k < QSPLIT; ++k) {
                cb += (double)cntpart[b2 * QSPLIT + k];
                l1num += (double)l1part[b2 * QSPLIT + k];
            }
            cnt[b2] = cb;
            msum += cb;
        }
        double l1 = l1num / msum;
        double cd = 0.0;
        for (int b2 = 0; b2 < BB; ++b2) {
            double chb = 0.0;
            for (int tk = 0; tk < 2; ++tk)
                for (int s = 0; s < 8; ++s)
                    chb += (double)ch[tk * 64 + b2 * 8 + s];
            cd += chb / cnt[b2];
        }
        cd *= (1.0 / BB);
        out[0] = (float)(l1 + exp(-l1) * cd);
    }
}

extern "C" void kernel_launch(void* const* d_in, const int* in_sizes, int n_in,
                              void* d_out, int out_size, void* d_ws, size_t ws_size,
                              hipStream_t stream) {
    const float* pred   = (const float*)d_in[0];
    const float* target = (const float*)d_in[1];
    const int*   mask   = (const int*)d_in[2];
    const float* points = (const float*)d_in[3];
    float* out = (float*)d_out;

    float* minpart  = (float*)d_ws;
    char* tail = (char*)d_ws + (size_t)MINPART_FLOATS * 4;
    float* champart = (float*)tail;
    float* l1part   = (float*)(tail + 512);
    float* cntpart  = (float*)(tail + 768);
    unsigned int* counter = (unsigned int*)(tail + 1024);

    k_main<<<2 * BB * QSPLIT * CSPLIT, BLK, 0, stream>>>(pred, target, points, mask,
                                                         minpart, l1part, cntpart, counter);
    k_redfin<<<128, BLK, 0, stream>>>(minpart, mask, l1part, cntpart,
                                      champart, counter, out);
}